// Round 1
// baseline (285.449 us; speedup 1.0000x reference)
//
#include <hip/hip_runtime.h>

#define NCOL 17
#define BLK  256
#define TILE_FLOATS (BLK * NCOL)      // 4352 floats = 17408 B per block (16B aligned)
#define TILE_VEC4   (TILE_FLOATS / 4) // 1088 float4

__global__ __launch_bounds__(BLK) void bsp_prime_kernel(
    const float* __restrict__ x, float* __restrict__ out, int n) {
    // C(15,k)
    const float C15[16] = {1.f, 15.f, 105.f, 455.f, 1365.f, 3003.f, 5005.f, 6435.f,
                           6435.f, 5005.f, 3003.f, 1365.f, 455.f, 105.f, 15.f, 1.f};

    __shared__ float tile[TILE_FLOATS];  // 17408 B -> 8 blocks/CU (wave-limited, not LDS)

    const int t = threadIdx.x;
    const int i = blockIdx.x * BLK + t;

    float y = (i < n) ? x[i] : 0.5f;
    // Reference's 0*log(0)=NaN -> zeroed rows at exact endpoints
    const bool edge = (y <= 0.0f) || (y >= 1.0f);
    const float omy = 1.0f - y;

    float yp[NCOL], op[NCOL];
    yp[0] = 1.0f;
    op[0] = 1.0f;
#pragma unroll
    for (int k = 1; k < NCOL; ++k) {
        yp[k] = yp[k - 1] * y;
        op[k] = op[k - 1] * omy;
    }

#pragma unroll
    for (int m = 0; m < NCOL; ++m) {
        float first = (m >= 1)  ? C15[m - 1] * yp[m - 1] * op[16 - m] : 0.0f;
        float sec   = (m <= 15) ? C15[m]     * yp[m]     * op[15 - m] : 0.0f;
        float v = 16.0f * (first - sec);
        // LDS write: stride-17 floats per lane -> 2-way bank alias (free on CDNA4)
        tile[t * NCOL + m] = edge ? 0.0f : v;
    }

    __syncthreads();

    // Coalesced drain: block covers a contiguous 4352-float span of out.
    // Vectorized: 1088 float4 per block = 4 full rounds of 256 + 64 remainder.
    // 16 B/lane global_store_dwordx4 instead of 17 scalar dword stores.
    const long long base  = (long long)blockIdx.x * TILE_FLOATS;
    const long long total = (long long)n * NCOL;

    if (base + TILE_FLOATS <= total) {
        const float4* __restrict__ s4 = (const float4*)tile;
        float4* __restrict__ o4 = (float4*)(out + base);
#pragma unroll
        for (int k = 0; k < 4; ++k) {
            o4[k * BLK + t] = s4[k * BLK + t];
        }
        if (t < TILE_VEC4 - 4 * BLK) {  // 64 leftover float4
            o4[4 * BLK + t] = s4[4 * BLK + t];
        }
    } else {
        // Generic tail path (unused at N=4M since 4M % 256 == 0)
        for (int k = 0; k < NCOL; ++k) {
            long long idx = base + (long long)k * BLK + t;
            if (idx < total) out[idx] = tile[k * BLK + t];
        }
    }
}

extern "C" void kernel_launch(void* const* d_in, const int* in_sizes, int n_in,
                              void* d_out, int out_size, void* d_ws, size_t ws_size,
                              hipStream_t stream) {
    const float* x = (const float*)d_in[0];
    float* out = (float*)d_out;
    const int n = in_sizes[0];  // 4,000,000 points
    const int grid = (n + BLK - 1) / BLK;
    bsp_prime_kernel<<<grid, BLK, 0, stream>>>(x, out, n);
}

// Round 2
// 280.900 us; speedup vs baseline: 1.0162x; 1.0162x over previous
//
#include <hip/hip_runtime.h>

#define NCOL 17
#define BLK  256
#define TILE_FLOATS (BLK * NCOL)      // 4352 floats = 17408 B per block (16B aligned)
#define TILE_VEC4   (TILE_FLOATS / 4) // 1088 float4
#define MAX_GRID    2048              // 256 CU x 8 resident blocks/CU (Guideline 11)

__global__ __launch_bounds__(BLK) void bsp_prime_kernel(
    const float* __restrict__ x, float* __restrict__ out, int n) {
    // C(15,k)
    const float C15[16] = {1.f, 15.f, 105.f, 455.f, 1365.f, 3003.f, 5005.f, 6435.f,
                           6435.f, 5005.f, 3003.f, 1365.f, 455.f, 105.f, 15.f, 1.f};

    __shared__ float tile[TILE_FLOATS];  // 17408 B -> 8 blocks/CU (wave-limited)

    const int t = threadIdx.x;
    const int ntiles = (n + BLK - 1) / BLK;
    const long long total = (long long)n * NCOL;

    // Persistent blocks: grid-stride over tiles so each block stays resident
    // and amortizes dispatch/teardown over ~8 tiles of streaming stores.
    for (int tb = blockIdx.x; tb < ntiles; tb += gridDim.x) {
        const int i = tb * BLK + t;
        float y = (i < n) ? x[i] : 0.5f;
        // Reference's 0*log(0)=NaN -> zeroed rows at exact endpoints
        const bool edge = (y <= 0.0f) || (y >= 1.0f);
        const float omy = 1.0f - y;

        float yp[NCOL], op[NCOL];
        yp[0] = 1.0f;
        op[0] = 1.0f;
#pragma unroll
        for (int k = 1; k < NCOL; ++k) {
            yp[k] = yp[k - 1] * y;
            op[k] = op[k - 1] * omy;
        }

        // sec(m) == first(m+1):  f[m] = C15[m-1]*yp[m-1]*op[16-m] (m=1..16)
        // v[m] = 16*(f[m] - f[m+1]),  f[0] = f[17] = 0
        float f[NCOL + 1];
        f[0] = 0.0f;
        f[NCOL] = 0.0f;
#pragma unroll
        for (int m = 1; m <= 16; ++m) {
            f[m] = C15[m - 1] * yp[m - 1] * op[16 - m];
        }

        __syncthreads();  // previous iteration's drain must finish before overwrite
#pragma unroll
        for (int m = 0; m < NCOL; ++m) {
            float v = 16.0f * (f[m] - f[m + 1]);
            // stride-17 floats per lane -> 2-way bank alias (free on CDNA4)
            tile[t * NCOL + m] = edge ? 0.0f : v;
        }
        __syncthreads();

        // Coalesced drain: tile covers a contiguous 4352-float span of out.
        const long long base = (long long)tb * TILE_FLOATS;
        if (base + TILE_FLOATS <= total) {
            const float4* __restrict__ s4 = (const float4*)tile;
            float4* __restrict__ o4 = (float4*)(out + base);
#pragma unroll
            for (int k = 0; k < 4; ++k) {
                o4[k * BLK + t] = s4[k * BLK + t];
            }
            if (t < TILE_VEC4 - 4 * BLK) {  // 64 leftover float4
                o4[4 * BLK + t] = s4[4 * BLK + t];
            }
        } else {
            // Generic tail path (unused at N=4M since 4M % 256 == 0)
            for (int k = 0; k < NCOL; ++k) {
                long long idx = base + (long long)k * BLK + t;
                if (idx < total) out[idx] = tile[k * BLK + t];
            }
        }
    }
}

extern "C" void kernel_launch(void* const* d_in, const int* in_sizes, int n_in,
                              void* d_out, int out_size, void* d_ws, size_t ws_size,
                              hipStream_t stream) {
    const float* x = (const float*)d_in[0];
    float* out = (float*)d_out;
    const int n = in_sizes[0];  // 4,000,000 points
    const int ntiles = (n + BLK - 1) / BLK;
    const int grid = ntiles < MAX_GRID ? ntiles : MAX_GRID;
    bsp_prime_kernel<<<grid, BLK, 0, stream>>>(x, out, n);
}